// Round 1
// 720.003 us; speedup vs baseline: 1.4186x; 1.4186x over previous
//
#include <hip/hip_runtime.h>
#include <hip/hip_bf16.h>

typedef __attribute__((ext_vector_type(8))) short s8v;
typedef __attribute__((ext_vector_type(4))) float f4v;
typedef __attribute__((ext_vector_type(4))) unsigned int u4v;

#define BATCH 32
#define SEQ   2048
#define DIM   256
#define ORIGIN_OFF ((size_t)BATCH * SEQ * DIM)

// ---- workspace layout (units: bf16 shorts) ----
// xT  [32][256][2048]  : x transposed per batch, bf16
// wlT [2048 q][256 k]  : wl_w^T bf16
// hisT[256 n][256 k]   : his_w^T bf16
// mlpT[256 n][256 k]   : mlp_w^T bf16
#define XT_OFF  0ull
#define WL_OFF  16777216ull
#define HIS_OFF 17301504ull
#define MLP_OFF 17367040ull
// total shorts 17432576 -> 34,865,152 bytes of d_ws

// ---- LDS layout (bytes), total 81408 (<= 81920 => 2 blocks/CU) ----
// A @ 0     : [64 rows][264 sh] stride 528   (x_bf16 -> Q_bf16 -> agg_bf16) 33792
// B @ 33792 : 46080-byte union:
//   S-phase : sK  [64 q][264 sh] stride 528 (full K=256)       33792
//   W-stage : sB  [128 n][72 sh] stride 144                    18432
//   PV      : sP  [64 m][72 sh] stride 144 @ +0                 9216
//             sXt [256 d][72 sh] stride 144 @ +9216             36864
//   epilog  : cg floats @ +24576 (1024), cb @ +25600
// C @ 79872 : 1536: stat_max[0,512) stat_sum[512,1024)
//             wp[0,1024) -> wcS[0,256), Ls[256,768), Lq[768,1280)
#define OFF_A 0
#define OFF_B 33792
#define OFF_C 79872

__device__ __forceinline__ unsigned short f2bf(float f) {
  __hip_bfloat16 h = __float2bfloat16(f);   // round-to-nearest-even
  return *reinterpret_cast<unsigned short*>(&h);
}
__device__ __forceinline__ f4v mfma16(s8v a, s8v b, f4v c) {
  return __builtin_amdgcn_mfma_f32_16x16x32_bf16(a, b, c, 0, 0, 0);
}
__device__ __forceinline__ unsigned int pk2(float lo, float hi) {
  return (unsigned int)f2bf(lo) | ((unsigned int)f2bf(hi) << 16);
}

// ---------------- prep kernels (run once per launch, tiny) ----------------

// transpose+convert weights: wl_w [256][2048] -> wlT [2048][256];
// his_w/mlp_w [256][256] -> [n][k] bf16.
__global__ __launch_bounds__(256) void prep_w(
    const float* __restrict__ wl_w, const float* __restrict__ his_w,
    const float* __restrict__ mlp_w, unsigned short* __restrict__ ws)
{
  const int gid = blockIdx.x * 256 + threadIdx.x;  // 320 blocks -> 2560 rows
  const int row = gid >> 5;
  const int c0 = (gid & 31) * 8;
  const float* src; unsigned short* dst; int ld;
  if (row < 2048)      { src = wl_w + row;          ld = 2048; dst = ws + WL_OFF  + (size_t)row * 256 + c0; }
  else if (row < 2304) { src = his_w + (row - 2048); ld = 256; dst = ws + HIS_OFF + (size_t)(row - 2048) * 256 + c0; }
  else                 { src = mlp_w + (row - 2304); ld = 256; dst = ws + MLP_OFF + (size_t)(row - 2304) * 256 + c0; }
  u4v o;
  #pragma unroll
  for (int j = 0; j < 4; ++j) {
    const unsigned short lo = f2bf(src[(size_t)(c0 + 2 * j) * ld]);
    const unsigned short hi = f2bf(src[(size_t)(c0 + 2 * j + 1) * ld]);
    o[j] = (unsigned int)lo | ((unsigned int)hi << 16);
  }
  *(u4v*)dst = o;
}

// transpose+convert x: x [b][p][d] f32 -> xT [b][d][p] bf16, 64x64 tiles.
__global__ __launch_bounds__(256) void prep_xt(
    const float* __restrict__ x, unsigned short* __restrict__ xT)
{
  __shared__ unsigned short tile[64][68];
  const int b = blockIdx.z, p0 = blockIdx.x * 64, d0 = blockIdx.y * 64;
  const int t = threadIdx.x;
  {
    const int r = t >> 2, c0 = (t & 3) * 16;
    const float* src = x + ((size_t)b * SEQ + p0 + r) * DIM + d0 + c0;
    #pragma unroll
    for (int j = 0; j < 4; ++j) {
      f4v v = *(const f4v*)(src + j * 4);
      tile[r][c0 + j * 4 + 0] = f2bf(v[0]);
      tile[r][c0 + j * 4 + 1] = f2bf(v[1]);
      tile[r][c0 + j * 4 + 2] = f2bf(v[2]);
      tile[r][c0 + j * 4 + 3] = f2bf(v[3]);
    }
  }
  __syncthreads();
  {
    const int dl = t >> 2, s0 = (t & 3) * 16;
    u4v o0, o1;
    #pragma unroll
    for (int j = 0; j < 4; ++j) {
      o0[j] = (unsigned int)tile[s0 + 2 * j][dl]     | ((unsigned int)tile[s0 + 2 * j + 1][dl] << 16);
      o1[j] = (unsigned int)tile[s0 + 8 + 2 * j][dl] | ((unsigned int)tile[s0 + 9 + 2 * j][dl] << 16);
    }
    unsigned short* dst = xT + ((size_t)b * DIM + d0 + dl) * SEQ + p0 + s0;
    *(u4v*)dst = o0;
    *(u4v*)(dst + 8) = o1;
  }
}

// ---------------- main kernel ----------------

// acc[a][nt] += (bf16 A-tile in region A) @ Wt(bf16 [n 256][k 256] row-major),
// staged through region B. n = wc*128 + nt*16 + col16.
__device__ __forceinline__ void gemm_x_w(
    const unsigned short* __restrict__ Wt, char* sA, char* sB,
    f4v (*acc)[8], int tid, int col16, int quad, int rw, int wc)
{
  for (int h2 = 0; h2 < 2; ++h2) {        // n-half of 128
    for (int kq = 0; kq < 4; ++kq) {      // k-quarter of 64
      __syncthreads();
      { // stage sB[n_local 128][k 64] bf16: pure vector copy
        const int nl = tid >> 1;          // 0..127
        const int ks = (tid & 1) * 32;    // k elems
        const unsigned short* src = Wt + (((size_t)(h2 * 128 + nl)) << 8) + kq * 64 + ks;
        char* dst = sB + nl * 144 + ks * 2;
        u4v tmp[4];
        #pragma unroll
        for (int j = 0; j < 4; ++j) tmp[j] = *(const u4v*)(src + j * 8);
        #pragma unroll
        for (int j = 0; j < 4; ++j) *(u4v*)(dst + j * 16) = tmp[j];
      }
      __syncthreads();
      if (wc == h2) {
        #pragma unroll
        for (int s2 = 0; s2 < 2; ++s2) {  // K=32 steps within quarter
          s8v afr[2];
          #pragma unroll
          for (int a = 0; a < 2; ++a) {
            const int row = rw + a * 16 + col16;
            const int o = kq * 8 + s2 * 4 + quad;
            afr[a] = *(const s8v*)(sA + row * 528 + o * 16);
          }
          #pragma unroll
          for (int nt = 0; nt < 8; ++nt) {
            const int nl2 = nt * 16 + col16;
            s8v bfr = *(const s8v*)(sB + nl2 * 144 + (s2 * 4 + quad) * 16);
            acc[0][nt] = mfma16(afr[0], bfr, acc[0][nt]);
            acc[1][nt] = mfma16(afr[1], bfr, acc[1][nt]);
          }
        }
      }
    }
  }
}

__global__ __launch_bounds__(256, 2)
void tfs_kernel(
    const float* __restrict__ x,
    const float* __restrict__ mlp_b,
    const float* __restrict__ his_b,
    const float* __restrict__ cur_w,
    const float* __restrict__ cur_b,
    const float* __restrict__ wl_b,
    const float* __restrict__ gate_w,
    const float* __restrict__ gate_b,
    const float* __restrict__ ln_g,
    const float* __restrict__ ln_b,
    const unsigned short* __restrict__ wsp,
    float* __restrict__ out)
{
  __shared__ __align__(16) char smem[81408];
  char* sA = smem + OFF_A;
  char* sB = smem + OFF_B;
  char* sC = smem + OFF_C;

  const int tid = threadIdx.x;
  const int lane = tid & 63;
  const int w = tid >> 6;
  const int col16 = lane & 15;
  const int quad = lane >> 4;
  const int wr = w & 1, wc = w >> 1;
  const int rw = wr * 32;
  const int b = blockIdx.y;
  const int p0 = blockIdx.x * 64;
  const float* xb = x + (size_t)b * SEQ * DIM;
  const unsigned short* wlT  = wsp + WL_OFF;
  const unsigned short* hisT = wsp + HIS_OFF;
  const unsigned short* mlpT = wsp + MLP_OFF;
  const unsigned short* xTb  = wsp + XT_OFF + (size_t)b * DIM * SEQ;
  const f4v zero4 = {0.f, 0.f, 0.f, 0.f};

  // ---- stage x p-rows into A as bf16 (once per block) ----
  {
    const int row = tid >> 2, cs = (tid & 3) * 64;
    const float* src = xb + (size_t)(p0 + row) * DIM + cs;
    char* dst = sA + row * 528 + cs * 2;
    #pragma unroll
    for (int j = 0; j < 8; ++j) {
      f4v a = *(const f4v*)(src + j * 8);
      f4v c = *(const f4v*)(src + j * 8 + 4);
      u4v o;
      o[0] = pk2(a[0], a[1]); o[1] = pk2(a[2], a[3]);
      o[2] = pk2(c[0], c[1]); o[3] = pk2(c[2], c[3]);
      *(u4v*)(dst + j * 16) = o;
    }
  }

  // ---- Q = x @ his_w + his_b (regs -> in-place bf16 into A) ----
  {
    f4v accQ[2][8];
    #pragma unroll
    for (int a = 0; a < 2; ++a)
      #pragma unroll
      for (int nt = 0; nt < 8; ++nt) accQ[a][nt] = zero4;
    gemm_x_w(hisT, sA, sB, accQ, tid, col16, quad, rw, wc);
    __syncthreads();   // all x reads done -> safe to overwrite A
    #pragma unroll
    for (int a = 0; a < 2; ++a)
      #pragma unroll
      for (int nt = 0; nt < 8; ++nt) {
        const int n = wc * 128 + nt * 16 + col16;
        const float bias = his_b[n];
        #pragma unroll
        for (int r = 0; r < 4; ++r) {
          const int row = rw + a * 16 + quad * 4 + r;
          *(unsigned short*)(sA + row * 528 + n * 2) = f2bf(accQ[a][nt][r] + bias);
        }
      }
  }

  // ---- flash loop ----
  f4v accO[2][8];
  #pragma unroll
  for (int a = 0; a < 2; ++a)
    #pragma unroll
    for (int dt = 0; dt < 8; ++dt) accO[a][dt] = zero4;
  float mrun[2][4], Zrun[2][4];
  #pragma unroll
  for (int a = 0; a < 2; ++a)
    #pragma unroll
    for (int r = 0; r < 4; ++r) { mrun[a][r] = -1.0e30f; Zrun[a][r] = 0.f; }

  float* stat_max = (float*)(sC);        // [2][64]
  float* stat_sum = (float*)(sC + 512);  // [2][64]

  for (int qi = 0; qi < 32; ++qi) {
    const int q0 = qi * 64;
    const bool active = (q0 <= p0);
    f4v accS[2][2];
    accS[0][0] = zero4; accS[0][1] = zero4; accS[1][0] = zero4; accS[1][1] = zero4;

    __syncthreads();                     // prior PV/sK consumers drained
    { // stage sK[64 q][256 k] bf16: vector copy of wlT rows q0..q0+63
      const int q = tid >> 2, seg = (tid & 3) * 64;
      const unsigned short* src = wlT + (((size_t)(q0 + q)) << 8) + seg;
      char* dst = sB + q * 528 + seg * 2;
      u4v tmp[8];
      #pragma unroll
      for (int j = 0; j < 8; ++j) tmp[j] = *(const u4v*)(src + j * 8);
      #pragma unroll
      for (int j = 0; j < 8; ++j) *(u4v*)(dst + j * 16) = tmp[j];
    }
    __syncthreads();

    // S = Q @ wl_w[:, q0:q0+64], full K=256 in one pass
    #pragma unroll
    for (int s = 0; s < 8; ++s) {
      s8v afr[2];
      #pragma unroll
      for (int a = 0; a < 2; ++a) {
        const int row = rw + a * 16 + col16;
        afr[a] = *(const s8v*)(sA + row * 528 + (s * 4 + quad) * 16);
      }
      #pragma unroll
      for (int t = 0; t < 2; ++t) {
        const int ql = wc * 32 + t * 16 + col16;
        s8v bfr = *(const s8v*)(sB + ql * 528 + (s * 4 + quad) * 16);
        accS[0][t] = mfma16(afr[0], bfr, accS[0][t]);
        accS[1][t] = mfma16(afr[1], bfr, accS[1][t]);
      }
    }

    // + wl_b
    #pragma unroll
    for (int t = 0; t < 2; ++t) {
      const float wlb = wl_b[q0 + wc * 32 + t * 16 + col16];
      #pragma unroll
      for (int a = 0; a < 2; ++a)
        #pragma unroll
        for (int r = 0; r < 4; ++r) accS[a][t][r] += wlb;
    }

    // row max
    float mx[2][4];
    #pragma unroll
    for (int a = 0; a < 2; ++a)
      #pragma unroll
      for (int r = 0; r < 4; ++r) {
        float v = fmaxf(accS[a][0][r], accS[a][1][r]);
        v = fmaxf(v, __shfl_xor(v, 1, 64));
        v = fmaxf(v, __shfl_xor(v, 2, 64));
        v = fmaxf(v, __shfl_xor(v, 4, 64));
        v = fmaxf(v, __shfl_xor(v, 8, 64));
        mx[a][r] = v;
      }
    if (col16 == 0) {
      #pragma unroll
      for (int a = 0; a < 2; ++a)
        #pragma unroll
        for (int r = 0; r < 4; ++r)
          stat_max[wc * 64 + rw + a * 16 + quad * 4 + r] = mx[a][r];
    }
    __syncthreads();                     // [B1] sK reads drained too

    float alpha[2][4];
    #pragma unroll
    for (int a = 0; a < 2; ++a)
      #pragma unroll
      for (int r = 0; r < 4; ++r) {
        const int row = rw + a * 16 + quad * 4 + r;
        const float mt = fmaxf(stat_max[row], stat_max[64 + row]);
        const float mn = fmaxf(mrun[a][r], mt);
        alpha[a][r] = __expf(fminf(mrun[a][r] - mn, 0.f));
        mrun[a][r] = mn;
      }

    float Pv[2][2][4];
    #pragma unroll
    for (int a = 0; a < 2; ++a)
      #pragma unroll
      for (int t = 0; t < 2; ++t)
        #pragma unroll
        for (int r = 0; r < 4; ++r)
          Pv[a][t][r] = __expf(fminf(accS[a][t][r] - mrun[a][r], 0.f));

    // row sums (unmasked denominator over all q)
    float ps[2][4];
    #pragma unroll
    for (int a = 0; a < 2; ++a)
      #pragma unroll
      for (int r = 0; r < 4; ++r) {
        float v = Pv[a][0][r] + Pv[a][1][r];
        v += __shfl_xor(v, 1, 64);
        v += __shfl_xor(v, 2, 64);
        v += __shfl_xor(v, 4, 64);
        v += __shfl_xor(v, 8, 64);
        ps[a][r] = v;
      }
    if (col16 == 0) {
      #pragma unroll
      for (int a = 0; a < 2; ++a)
        #pragma unroll
        for (int r = 0; r < 4; ++r)
          stat_sum[wc * 64 + rw + a * 16 + quad * 4 + r] = ps[a][r];
    }

    if (active) { // masked P (tril, q<=p) -> sP bf16 (safe after B1)
      #pragma unroll
      for (int a = 0; a < 2; ++a)
        #pragma unroll
        for (int t = 0; t < 2; ++t)
          #pragma unroll
          for (int r = 0; r < 4; ++r) {
            const int row = rw + a * 16 + quad * 4 + r;
            const int ql = wc * 32 + t * 16 + col16;
            const float pv = ((q0 + ql) <= (p0 + row)) ? Pv[a][t][r] : 0.f;
            *(unsigned short*)(sB + row * 144 + ql * 2) = f2bf(pv);
          }
    }
    __syncthreads();                     // [B2] stats + sP visible

    if (active) { // stage sXt[256 d][64 q] bf16: vector copy of xT rows
      const int d = tid;
      const unsigned short* src = xTb + ((size_t)d << 11) + q0;
      char* dst = sB + 9216 + d * 144;
      u4v tmp[8];
      #pragma unroll
      for (int j = 0; j < 8; ++j) tmp[j] = *(const u4v*)(src + j * 8);
      #pragma unroll
      for (int j = 0; j < 8; ++j) *(u4v*)(dst + j * 16) = tmp[j];
    }

    #pragma unroll
    for (int a = 0; a < 2; ++a)
      #pragma unroll
      for (int r = 0; r < 4; ++r) {
        const int row = rw + a * 16 + quad * 4 + r;
        const float st = stat_sum[row] + stat_sum[64 + row];
        Zrun[a][r] = Zrun[a][r] * alpha[a][r] + st;
      }
    #pragma unroll
    for (int a = 0; a < 2; ++a)
      #pragma unroll
      for (int dt = 0; dt < 8; ++dt)
        #pragma unroll
        for (int r = 0; r < 4; ++r) accO[a][dt][r] *= alpha[a][r];

    if (active) {
      __syncthreads();                   // sXt visible
      #pragma unroll
      for (int h = 0; h < 2; ++h) {
        s8v ap[2];
        #pragma unroll
        for (int a = 0; a < 2; ++a) {
          const int row = rw + a * 16 + col16;
          ap[a] = *(const s8v*)(sB + row * 144 + (h * 4 + quad) * 16);
        }
        #pragma unroll
        for (int dt = 0; dt < 8; ++dt) {
          const int d = wc * 128 + dt * 16 + col16;
          s8v bv = *(const s8v*)(sB + 9216 + d * 144 + (h * 4 + quad) * 16);
          accO[0][dt] = mfma16(ap[0], bv, accO[0][dt]);
          accO[1][dt] = mfma16(ap[1], bv, accO[1][dt]);
        }
      }
    }
  } // qi

  // ---- epilogue: agg = O/Z -> A (bf16) ----
  __syncthreads();
  #pragma unroll
  for (int a = 0; a < 2; ++a)
    #pragma unroll
    for (int dt = 0; dt < 8; ++dt) {
      const int n = wc * 128 + dt * 16 + col16;
      #pragma unroll
      for (int r = 0; r < 4; ++r) {
        const int row = rw + a * 16 + quad * 4 + r;
        const float invZ = 1.0f / fmaxf(Zrun[a][r], 1e-30f);
        *(unsigned short*)(sA + row * 528 + n * 2) = f2bf(accO[a][dt][r] * invZ);
      }
    }

  // ---- H_hist = agg @ mlp_w ----
  f4v accH[2][8];
  #pragma unroll
  for (int a = 0; a < 2; ++a)
    #pragma unroll
    for (int nt = 0; nt < 8; ++nt) accH[a][nt] = zero4;
  gemm_x_w(mlpT, sA, sB, accH, tid, col16, quad, rw, wc);
  __syncthreads();

  // ---- cg[d] = cur_w[d,:]·gate_w ; cb ----
  float* cgL = (float*)(sB + 24576);
  float* cbL = (float*)(sB + 25600);
  {
    const float* cw = cur_w + (size_t)tid * DIM;
    float s = 0.f;
    #pragma unroll 8
    for (int i = 0; i < 64; ++i) {
      f4v vc = *(const f4v*)(cw + i * 4);
      f4v vg = *(const f4v*)(gate_w + i * 4);
      s += vc[0] * vg[0] + vc[1] * vg[1] + vc[2] * vg[2] + vc[3] * vg[3];
    }
    cgL[tid] = s;
    if (tid == 0) {
      float s2 = 0.f;
      for (int j = 0; j < DIM; ++j) s2 += cur_b[j] * gate_w[j];
      cbL[0] = s2 + gate_b[0];
    }
  }
  __syncthreads();

  // ---- wc[p] = x[p]·cg + cb (x from global, fp32) ----
  float* wp = (float*)sC;          // [64][4]
  {
    const int row = tid & 63, sg = tid >> 6;
    const float* xr = xb + (size_t)(p0 + row) * DIM + sg * 64;
    const float* cgp = cgL + sg * 64;
    float sacc = 0.f;
    #pragma unroll
    for (int i = 0; i < 16; ++i) {
      f4v xv4 = *(const f4v*)(xr + i * 4);
      sacc += xv4[0] * cgp[i * 4] + xv4[1] * cgp[i * 4 + 1]
            + xv4[2] * cgp[i * 4 + 2] + xv4[3] * cgp[i * 4 + 3];
    }
    wp[row * 4 + sg] = sacc;
  }
  __syncthreads();
  float* wcS = (float*)sC;         // [64], wave-0 own-slot overwrite
  if (tid < 64) {
    const float v = wp[tid * 4] + wp[tid * 4 + 1] + wp[tid * 4 + 2] + wp[tid * 4 + 3] + cbL[0];
    wcS[tid] = v;
  }
  __syncthreads();

  // ---- h = H_hist + mlp_b + wc*x ; LN ----
  float s1l[2][4], s2l[2][4];
  #pragma unroll
  for (int a = 0; a < 2; ++a)
    #pragma unroll
    for (int r = 0; r < 4; ++r) { s1l[a][r] = 0.f; s2l[a][r] = 0.f; }
  #pragma unroll
  for (int a = 0; a < 2; ++a)
    #pragma unroll
    for (int nt = 0; nt < 8; ++nt) {
      const int n = wc * 128 + nt * 16 + col16;
      const float mb = mlp_b[n];
      #pragma unroll
      for (int r = 0; r < 4; ++r) {
        const int row = rw + a * 16 + quad * 4 + r;
        const float xv = xb[(size_t)(p0 + row) * DIM + n];
        const float v = accH[a][nt][r] + mb + wcS[row] * xv;
        accH[a][nt][r] = v;
        s1l[a][r] += v;
        s2l[a][r] += v * v;
      }
    }
  #pragma unroll
  for (int a = 0; a < 2; ++a)
    #pragma unroll
    for (int r = 0; r < 4; ++r) {
      float v1 = s1l[a][r], v2 = s2l[a][r];
      v1 += __shfl_xor(v1, 1, 64); v2 += __shfl_xor(v2, 1, 64);
      v1 += __shfl_xor(v1, 2, 64); v2 += __shfl_xor(v2, 2, 64);
      v1 += __shfl_xor(v1, 4, 64); v2 += __shfl_xor(v2, 4, 64);
      v1 += __shfl_xor(v1, 8, 64); v2 += __shfl_xor(v2, 8, 64);
      s1l[a][r] = v1; s2l[a][r] = v2;
    }
  float* Ls = (float*)(sC + 256);  // [2][64]
  float* Lq = (float*)(sC + 768);  // [2][64]
  if (col16 == 0) {
    #pragma unroll
    for (int a = 0; a < 2; ++a)
      #pragma unroll
      for (int r = 0; r < 4; ++r) {
        const int row = rw + a * 16 + quad * 4 + r;
        Ls[wc * 64 + row] = s1l[a][r];
        Lq[wc * 64 + row] = s2l[a][r];
      }
  }
  __syncthreads();

  #pragma unroll
  for (int a = 0; a < 2; ++a) {
    float mean_[4], rstd_[4];
    #pragma unroll
    for (int r = 0; r < 4; ++r) {
      const int row = rw + a * 16 + quad * 4 + r;
      const float S1 = Ls[row] + Ls[64 + row];
      const float S2 = Lq[row] + Lq[64 + row];
      const float mean = S1 * (1.0f / 256.0f);
      const float var = S2 * (1.0f / 256.0f) - mean * mean;
      mean_[r] = mean;
      rstd_[r] = rsqrtf(fmaxf(var, 0.f) + 1e-5f);
    }
    #pragma unroll
    for (int nt = 0; nt < 8; ++nt) {
      const int n = wc * 128 + nt * 16 + col16;
      const float g = ln_g[n];
      const float be = ln_b[n];
      #pragma unroll
      for (int r = 0; r < 4; ++r) {
        const int row = rw + a * 16 + quad * 4 + r;
        const float y = (accH[a][nt][r] - mean_[r]) * rstd_[r] * g + be;
        out[((size_t)b * SEQ + p0 + row) * DIM + n] = y;
      }
    }
  }

  // ---- origin passthrough: direct fp32 global->global ----
  {
    const int row = tid >> 2, cs = (tid & 3) * 64;
    const float* src = xb + (size_t)(p0 + row) * DIM + cs;
    float* dst = out + ORIGIN_OFF + ((size_t)b * SEQ + p0 + row) * DIM + cs;
    #pragma unroll
    for (int j = 0; j < 16; ++j)
      *(f4v*)(dst + j * 4) = *(const f4v*)(src + j * 4);
  }
}

extern "C" void kernel_launch(void* const* d_in, const int* in_sizes, int n_in,
                              void* d_out, int out_size, void* d_ws, size_t ws_size,
                              hipStream_t stream) {
  const float* x      = (const float*)d_in[0];
  const float* mlp_w  = (const float*)d_in[1];
  const float* mlp_b  = (const float*)d_in[2];
  const float* his_w  = (const float*)d_in[3];
  const float* his_b  = (const float*)d_in[4];
  const float* cur_w  = (const float*)d_in[5];
  const float* cur_b  = (const float*)d_in[6];
  const float* wl_w   = (const float*)d_in[7];
  const float* wl_b   = (const float*)d_in[8];
  const float* gate_w = (const float*)d_in[9];
  const float* gate_b = (const float*)d_in[10];
  const float* ln_g   = (const float*)d_in[11];
  const float* ln_b   = (const float*)d_in[12];

  unsigned short* ws = (unsigned short*)d_ws;

  prep_w<<<dim3(320), 256, 0, stream>>>(wl_w, his_w, mlp_w, ws);
  prep_xt<<<dim3(32, 4, 32), 256, 0, stream>>>(x, ws + XT_OFF);
  tfs_kernel<<<dim3(32, 32), 256, 0, stream>>>(
      x, mlp_b, his_b, cur_w, cur_b, wl_b, gate_w, gate_b,
      ln_g, ln_b, ws, (float*)d_out);
}

// Round 2
// 494.173 us; speedup vs baseline: 2.0669x; 1.4570x over previous
//
#include <hip/hip_runtime.h>
#include <hip/hip_bf16.h>

typedef __attribute__((ext_vector_type(8))) short s8v;
typedef __attribute__((ext_vector_type(4))) float f4v;
typedef __attribute__((ext_vector_type(4))) unsigned int u4v;

#define BATCH 32
#define SEQ   2048
#define DIM   256
#define ORIGIN_OFF ((size_t)BATCH * SEQ * DIM)

// ---- workspace layout (units: bf16 shorts) ----
// xT  [32][256][2048]  : x transposed per batch, bf16
// wlT [2048 q][256 k]  : wl_w^T bf16
// hisT[256 n][256 k]   : his_w^T bf16
// mlpT[256 n][256 k]   : mlp_w^T bf16
#define XT_OFF  0ull
#define WL_OFF  16777216ull
#define HIS_OFF 17301504ull
#define MLP_OFF 17367040ull

// ---- LDS layout (bytes), total 81408 (2 blocks/CU) ----
// A @ 0     : phase1: x/Q/agg [64 rows][264 sh] stride 528 (33792)
//             flash : sK [64 q][512B] linear+XOR-swizzled chunks (32768)
// B @ 33792 : flash : sP [64 p][72 sh] stride 144 @ +0 (9216)
//                     sXt [256 d][128B] swizzled @ +9216 (32768)
//             gemm  : W-stage [64 n][512B] swizzled @ +0 (32768)
//             epilog: cg floats @ +24576 (1024), cb @ +25600
// C @ 79872 : stat_max[0,512) stat_sum[512,1024)
//             wp[0,1024) -> wcS[0,256), Ls[256,768), Lq[768,1280)
#define OFF_A 0
#define OFF_B 33792
#define OFF_C 79872
#define XT_LDS 9216

__device__ __forceinline__ unsigned short f2bf(float f) {
  __hip_bfloat16 h = __float2bfloat16(f);   // round-to-nearest-even
  return *reinterpret_cast<unsigned short*>(&h);
}
__device__ __forceinline__ f4v mfma16(s8v a, s8v b, f4v c) {
  return __builtin_amdgcn_mfma_f32_16x16x32_bf16(a, b, c, 0, 0, 0);
}
__device__ __forceinline__ unsigned int pk2(float lo, float hi) {
  return (unsigned int)f2bf(lo) | ((unsigned int)f2bf(hi) << 16);
}
// async global->LDS, 16B per lane; LDS dest = wave-uniform base + lane*16
__device__ __forceinline__ void dma16(const void* g, void* l) {
  __builtin_amdgcn_global_load_lds(
      (const __attribute__((address_space(1))) unsigned int*)g,
      (__attribute__((address_space(3))) unsigned int*)l, 16, 0, 0);
}

// ---------------- prep kernels (run once per launch, tiny) ----------------

__global__ __launch_bounds__(256) void prep_w(
    const float* __restrict__ wl_w, const float* __restrict__ his_w,
    const float* __restrict__ mlp_w, unsigned short* __restrict__ ws)
{
  const int gid = blockIdx.x * 256 + threadIdx.x;  // 320 blocks -> 2560 rows
  const int row = gid >> 5;
  const int c0 = (gid & 31) * 8;
  const float* src; unsigned short* dst; int ld;
  if (row < 2048)      { src = wl_w + row;           ld = 2048; dst = ws + WL_OFF  + (size_t)row * 256 + c0; }
  else if (row < 2304) { src = his_w + (row - 2048); ld = 256;  dst = ws + HIS_OFF + (size_t)(row - 2048) * 256 + c0; }
  else                 { src = mlp_w + (row - 2304); ld = 256;  dst = ws + MLP_OFF + (size_t)(row - 2304) * 256 + c0; }
  u4v o;
  #pragma unroll
  for (int j = 0; j < 4; ++j) {
    const unsigned short lo = f2bf(src[(size_t)(c0 + 2 * j) * ld]);
    const unsigned short hi = f2bf(src[(size_t)(c0 + 2 * j + 1) * ld]);
    o[j] = (unsigned int)lo | ((unsigned int)hi << 16);
  }
  *(u4v*)dst = o;
}

__global__ __launch_bounds__(256) void prep_xt(
    const float* __restrict__ x, unsigned short* __restrict__ xT)
{
  __shared__ unsigned short tile[64][68];
  const int b = blockIdx.z, p0 = blockIdx.x * 64, d0 = blockIdx.y * 64;
  const int t = threadIdx.x;
  {
    const int r = t >> 2, c0 = (t & 3) * 16;
    const float* src = x + ((size_t)b * SEQ + p0 + r) * DIM + d0 + c0;
    #pragma unroll
    for (int j = 0; j < 4; ++j) {
      f4v v = *(const f4v*)(src + j * 4);
      tile[r][c0 + j * 4 + 0] = f2bf(v[0]);
      tile[r][c0 + j * 4 + 1] = f2bf(v[1]);
      tile[r][c0 + j * 4 + 2] = f2bf(v[2]);
      tile[r][c0 + j * 4 + 3] = f2bf(v[3]);
    }
  }
  __syncthreads();
  {
    const int dl = t >> 2, s0 = (t & 3) * 16;
    u4v o0, o1;
    #pragma unroll
    for (int j = 0; j < 4; ++j) {
      o0[j] = (unsigned int)tile[s0 + 2 * j][dl]     | ((unsigned int)tile[s0 + 2 * j + 1][dl] << 16);
      o1[j] = (unsigned int)tile[s0 + 8 + 2 * j][dl] | ((unsigned int)tile[s0 + 9 + 2 * j][dl] << 16);
    }
    unsigned short* dst = xT + ((size_t)b * DIM + d0 + dl) * SEQ + p0 + s0;
    *(u4v*)dst = o0;
    *(u4v*)(dst + 8) = o1;
  }
}

// ---------------- main kernel ----------------

// acc[a][st*2+nt] += A(regs af) @ Wt(bf16 [n 256][k 256]); 4 full-K stages of
// 64 n-columns each, staged by global_load_lds into swizzled [64][512B] LDS.
__device__ __forceinline__ void gemm_regA(
    const unsigned short* __restrict__ Wt,
    const s8v (&af)[2][8], f4v (&acc)[2][8],
    char* smem_, int tid, int col16, int quad, int wc, int x7, int wq)
{
  char* sB = smem_ + OFF_B;
  char* ldsW = sB + wq * 1024;
  const int wrow = tid >> 5;            // 0..7
  const int wu = (tid & 31) ^ wrow;     // pre-swizzled source chunk
  for (int st = 0; st < 4; ++st) {
    if (st) __syncthreads();            // prior-stage reads drained
    const unsigned short* src = Wt + (size_t)(st * 64 + wrow) * 256 + wu * 8;
    #pragma unroll
    for (int j = 0; j < 8; ++j) dma16(src + (size_t)j * 2048, ldsW + j * 4096);
    __syncthreads();                    // DMA complete (implicit vmcnt(0))
    #pragma unroll
    for (int s = 0; s < 8; ++s) {
      const int sl = (((s * 4 + quad) ^ x7) << 4);
      #pragma unroll
      for (int nt = 0; nt < 2; ++nt) {
        s8v bfr = *(const s8v*)(sB + (wc * 32 + nt * 16 + col16) * 512 + sl);
        acc[0][st * 2 + nt] = mfma16(af[0][s], bfr, acc[0][st * 2 + nt]);
        acc[1][st * 2 + nt] = mfma16(af[1][s], bfr, acc[1][st * 2 + nt]);
      }
    }
  }
}

__global__ __launch_bounds__(256, 2)
void tfs_kernel(
    const float* __restrict__ x,
    const float* __restrict__ mlp_b,
    const float* __restrict__ his_b,
    const float* __restrict__ cur_w,
    const float* __restrict__ cur_b,
    const float* __restrict__ wl_b,
    const float* __restrict__ gate_w,
    const float* __restrict__ gate_b,
    const float* __restrict__ ln_g,
    const float* __restrict__ ln_b,
    const unsigned short* __restrict__ wsp,
    float* __restrict__ out)
{
  __shared__ __align__(16) char smem[81408];
  char* sA = smem + OFF_A;
  char* sB = smem + OFF_B;
  char* sC = smem + OFF_C;

  const int tid = threadIdx.x;
  const int lane = tid & 63;
  const int col16 = lane & 15;
  const int quad = lane >> 4;
  const int w = tid >> 6;
  const int wr = w & 1, wc = w >> 1;
  const int rw = wr * 32;
  const int x7 = col16 & 7;
  const int wq = __builtin_amdgcn_readfirstlane(w);

  // load-balance remap: each CU's 4 sequential blocks get p-tiles spaced by 8
  const int b = blockIdx.y;
  const int pidx = (blockIdx.x + ((blockIdx.y >> 3) & 3) * 8) & 31;
  const int p0 = pidx * 64;

  const float* xb = x + (size_t)b * SEQ * DIM;
  const unsigned short* wlT  = wsp + WL_OFF;
  const unsigned short* hisT = wsp + HIS_OFF;
  const unsigned short* mlpT = wsp + MLP_OFF;
  const unsigned short* xTb  = wsp + XT_OFF + (size_t)b * DIM * SEQ;
  const f4v zero4 = {0.f, 0.f, 0.f, 0.f};

  // DMA lane-role constants (pre-swizzled global sources, linear LDS dest)
  const int krow = tid >> 5;                // 0..7   (sK: row step 8/instr)
  const int ku   = (tid & 31) ^ krow;       // chunk within 512B row
  const int xrow = tid >> 3;                // 0..31  (sXt: row step 32/instr)
  const int xu   = (tid & 7) ^ (xrow & 7);  // chunk within 128B row
  char* ldsK = smem + OFF_A + wq * 1024;
  char* ldsX = smem + OFF_B + XT_LDS + wq * 1024;

  // ---- x fragments direct from global (bf16-converted, A-layout) ----
  s8v xf[2][8];
  #pragma unroll
  for (int a = 0; a < 2; ++a) {
    const int row = rw + a * 16 + col16;
    const float* srcx = xb + (size_t)(p0 + row) * DIM;
    #pragma unroll
    for (int s = 0; s < 8; ++s) {
      const int k0 = (s * 4 + quad) * 8;
      f4v v0 = *(const f4v*)(srcx + k0);
      f4v v1 = *(const f4v*)(srcx + k0 + 4);
      u4v o;
      o[0] = pk2(v0[0], v0[1]); o[1] = pk2(v0[2], v0[3]);
      o[2] = pk2(v1[0], v1[1]); o[3] = pk2(v1[2], v1[3]);
      xf[a][s] = *(s8v*)&o;
    }
  }

  // ---- Q = x @ his_w + his_b ----
  f4v accQ[2][8];
  #pragma unroll
  for (int a = 0; a < 2; ++a)
    #pragma unroll
    for (int i = 0; i < 8; ++i) accQ[a][i] = zero4;
  gemm_regA(hisT, xf, accQ, smem, tid, col16, quad, wc, x7, wq);
  // writeback Q -> sA bf16 (stride 528)
  #pragma unroll
  for (int a = 0; a < 2; ++a)
    #pragma unroll
    for (int i = 0; i < 8; ++i) {
      const int n = (i >> 1) * 64 + wc * 32 + (i & 1) * 16 + col16;
      const float bias = his_b[n];
      #pragma unroll
      for (int r = 0; r < 4; ++r) {
        const int row = rw + a * 16 + quad * 4 + r;
        *(unsigned short*)(sA + row * 528 + n * 2) = f2bf(accQ[a][i][r] + bias);
      }
    }
  __syncthreads();                         // Q visible
  // Q fragments -> regs (qi-invariant!)
  s8v qf[2][8];
  #pragma unroll
  for (int a = 0; a < 2; ++a) {
    const int row = rw + a * 16 + col16;
    #pragma unroll
    for (int s = 0; s < 8; ++s)
      qf[a][s] = *(const s8v*)(sA + row * 528 + (s * 4 + quad) * 16);
  }
  __syncthreads();                         // all qf reads done; region A free
  // stage sK(0) via DMA
  {
    const unsigned short* srck = wlT + (size_t)krow * 256 + ku * 8;
    #pragma unroll
    for (int j = 0; j < 8; ++j) dma16(srck + (size_t)j * 2048, ldsK + j * 4096);
  }
  __syncthreads();                         // sK(0) ready

  // ---- flash loop ----
  f4v accO[2][8];
  #pragma unroll
  for (int a = 0; a < 2; ++a)
    #pragma unroll
    for (int dt = 0; dt < 8; ++dt) accO[a][dt] = zero4;
  float mrun[2][4], Zrun[2][4], mrunT[2];
  #pragma unroll
  for (int a = 0; a < 2; ++a) {
    mrunT[a] = -1.0e30f;
    #pragma unroll
    for (int r = 0; r < 4; ++r) { mrun[a][r] = -1.0e30f; Zrun[a][r] = 0.f; }
  }
  float* stat_max = (float*)(sC);        // [2][64]
  float* stat_sum = (float*)(sC + 512);  // [2][64]
  char* sX = sB + XT_LDS;
  const int rk0 = (wc * 32 + col16) * 512;
  const int rk1 = rk0 + 16 * 512;

  #pragma unroll 1
  for (int qi = 0; qi < 32; ++qi) {
    const int q0 = qi * 64;
    const bool active = (q0 <= p0);

    // --- S^T = K @ Q (swapped operands: p lands on col16, q on quad*4+r) ---
    f4v accST[2][2];
    accST[0][0] = zero4; accST[0][1] = zero4;
    accST[1][0] = zero4; accST[1][1] = zero4;
    #pragma unroll
    for (int s = 0; s < 8; ++s) {
      const int sl = (((s * 4 + quad) ^ x7) << 4);
      s8v kf0 = *(const s8v*)(sA + rk0 + sl);
      s8v kf1 = *(const s8v*)(sA + rk1 + sl);
      accST[0][0] = mfma16(kf0, qf[0][s], accST[0][0]);
      accST[0][1] = mfma16(kf0, qf[1][s], accST[0][1]);
      accST[1][0] = mfma16(kf1, qf[0][s], accST[1][0]);
      accST[1][1] = mfma16(kf1, qf[1][s], accST[1][1]);
    }
    // + wl_b (vector: 4 consecutive q per lane)
    #pragma unroll
    for (int t = 0; t < 2; ++t) {
      const f4v wb = *(const f4v*)(wl_b + q0 + wc * 32 + t * 16 + quad * 4);
      #pragma unroll
      for (int a = 0; a < 2; ++a)
        #pragma unroll
        for (int r = 0; r < 4; ++r) accST[t][a][r] += wb[r];
    }
    // tile row-max per a: in-lane over 8, cross-quad via 2 shuffles
    #pragma unroll
    for (int a = 0; a < 2; ++a) {
      float m = fmaxf(fmaxf(fmaxf(accST[0][a][0], accST[0][a][1]),
                            fmaxf(accST[0][a][2], accST[0][a][3])),
                      fmaxf(fmaxf(accST[1][a][0], accST[1][a][1]),
                            fmaxf(accST[1][a][2], accST[1][a][3])));
      m = fmaxf(m, __shfl_xor(m, 16, 64));
      m = fmaxf(m, __shfl_xor(m, 32, 64));
      if (quad == 0) stat_max[wc * 64 + rw + a * 16 + col16] = m;
    }
    __syncthreads();                     // [B1] stats visible; sK/sXt/sP turnover

    // prefetch DMAs early; drained for free by B2's implicit vmcnt(0)
    if (qi < 31) {                       // sK(qi+1) into region A
      const unsigned short* srck = wlT + (size_t)(q0 + 64 + krow) * 256 + ku * 8;
      #pragma unroll
      for (int j = 0; j < 8; ++j) dma16(srck + (size_t)j * 2048, ldsK + j * 4096);
    }
    if (active) {                        // sXt(qi) into region B
      const unsigned short* srcx = xTb + (size_t)xrow * 2048 + q0 + xu * 8;
      #pragma unroll
      for (int j = 0; j < 8; ++j) dma16(srcx + (size_t)j * 65536, ldsX + j * 4096);
    }

    // alpha for accO rows (old mapping)
    float alpha[2][4];
    #pragma unroll
    for (int a = 0; a < 2; ++a)
      #pragma unroll
      for (int r = 0; r < 4; ++r) {
        const int row = rw + a * 16 + quad * 4 + r;
        const float mt = fmaxf(stat_max[row], stat_max[64 + row]);
        const float mn = fmaxf(mrun[a][r], mt);
        alpha[a][r] = __expf(fminf(mrun[a][r] - mn, 0.f));
        mrun[a][r] = mn;
      }
    // running max in S^T mapping (p = rw + a*16 + col16)
    #pragma unroll
    for (int a = 0; a < 2; ++a) {
      const int p = rw + a * 16 + col16;
      mrunT[a] = fmaxf(mrunT[a], fmaxf(stat_max[p], stat_max[64 + p]));
    }
    // P = exp(S - m)
    float Pv[2][2][4];
    #pragma unroll
    for (int t = 0; t < 2; ++t)
      #pragma unroll
      for (int a = 0; a < 2; ++a)
        #pragma unroll
        for (int r = 0; r < 4; ++r)
          Pv[t][a][r] = __expf(fminf(accST[t][a][r] - mrunT[a], 0.f));
    // row sums: in-lane 8 + 2 shuffles
    #pragma unroll
    for (int a = 0; a < 2; ++a) {
      float s = ((Pv[0][a][0] + Pv[0][a][1]) + (Pv[0][a][2] + Pv[0][a][3]))
              + ((Pv[1][a][0] + Pv[1][a][1]) + (Pv[1][a][2] + Pv[1][a][3]));
      s += __shfl_xor(s, 16, 64);
      s += __shfl_xor(s, 32, 64);
      if (quad == 0) stat_sum[wc * 64 + rw + a * 16 + col16] = s;
    }
    // masked P -> sP bf16
    if (active) {
      #pragma unroll
      for (int t = 0; t < 2; ++t)
        #pragma unroll
        for (int a = 0; a < 2; ++a) {
          const int p = rw + a * 16 + col16;
          #pragma unroll
          for (int r = 0; r < 4; ++r) {
            const int ql = wc * 32 + t * 16 + quad * 4 + r;
            const float pv = ((q0 + ql) <= (p0 + p)) ? Pv[t][a][r] : 0.f;
            *(unsigned short*)(sB + p * 144 + ql * 2) = f2bf(pv);
          }
        }
    }
    __syncthreads();                     // [B2] sP/sXt/sK(qi+1)/stat_sum ready

    // Z update + O rescale
    #pragma unroll
    for (int a = 0; a < 2; ++a)
      #pragma unroll
      for (int r = 0; r < 4; ++r) {
        const int row = rw + a * 16 + quad * 4 + r;
        const float st = stat_sum[row] + stat_sum[64 + row];
        Zrun[a][r] = Zrun[a][r] * alpha[a][r] + st;
      }
    #pragma unroll
    for (int a = 0; a < 2; ++a)
      #pragma unroll
      for (int dt = 0; dt < 8; ++dt)
        #pragma unroll
        for (int r = 0; r < 4; ++r) accO[a][dt][r] *= alpha[a][r];

    if (active) {                        // PV
      #pragma unroll
      for (int h = 0; h < 2; ++h) {
        s8v ap0 = *(const s8v*)(sB + (rw + col16) * 144 + (h * 4 + quad) * 16);
        s8v ap1 = *(const s8v*)(sB + (rw + 16 + col16) * 144 + (h * 4 + quad) * 16);
        const int slx = (((h * 4 + quad) ^ x7) << 4);
        #pragma unroll
        for (int dt = 0; dt < 8; ++dt) {
          const int d = wc * 128 + dt * 16 + col16;
          s8v bv = *(const s8v*)(sX + d * 128 + slx);
          accO[0][dt] = mfma16(ap0, bv, accO[0][dt]);
          accO[1][dt] = mfma16(ap1, bv, accO[1][dt]);
        }
      }
    }
  } // qi

  // ---- epilogue: agg = O/Z -> sA (bf16, stride 528) ----
  #pragma unroll
  for (int a = 0; a < 2; ++a)
    #pragma unroll
    for (int dt = 0; dt < 8; ++dt) {
      const int d = wc * 128 + dt * 16 + col16;
      #pragma unroll
      for (int r = 0; r < 4; ++r) {
        const int row = rw + a * 16 + quad * 4 + r;
        const float invZ = 1.0f / fmaxf(Zrun[a][r], 1e-30f);
        *(unsigned short*)(sA + row * 528 + d * 2) = f2bf(accO[a][dt][r] * invZ);
      }
    }
  __syncthreads();                       // agg visible; PV readers drained
  s8v af[2][8];
  #pragma unroll
  for (int a = 0; a < 2; ++a) {
    const int row = rw + a * 16 + col16;
    #pragma unroll
    for (int s = 0; s < 8; ++s)
      af[a][s] = *(const s8v*)(sA + row * 528 + (s * 4 + quad) * 16);
  }
  // ---- H_hist = agg @ mlp_w ----
  f4v accH[2][8];
  #pragma unroll
  for (int a = 0; a < 2; ++a)
    #pragma unroll
    for (int i = 0; i < 8; ++i) accH[a][i] = zero4;
  gemm_regA(mlpT, af, accH, smem, tid, col16, quad, wc, x7, wq);
  __syncthreads();

  // ---- cg[d] = cur_w[d,:]·gate_w ; cb ----
  float* cgL = (float*)(sB + 24576);
  float* cbL = (float*)(sB + 25600);
  {
    const float* cw = cur_w + (size_t)tid * DIM;
    float s = 0.f;
    #pragma unroll 8
    for (int i = 0; i < 64; ++i) {
      f4v vc = *(const f4v*)(cw + i * 4);
      f4v vg = *(const f4v*)(gate_w + i * 4);
      s += vc[0] * vg[0] + vc[1] * vg[1] + vc[2] * vg[2] + vc[3] * vg[3];
    }
    cgL[tid] = s;
    if (tid == 0) {
      float s2 = 0.f;
      for (int j = 0; j < DIM; ++j) s2 += cur_b[j] * gate_w[j];
      cbL[0] = s2 + gate_b[0];
    }
  }
  __syncthreads();

  // ---- wc[p] = x[p]·cg + cb ----
  float* wp = (float*)sC;
  {
    const int row = tid & 63, sg = tid >> 6;
    const float* xr = xb + (size_t)(p0 + row) * DIM + sg * 64;
    const float* cgp = cgL + sg * 64;
    float sacc = 0.f;
    #pragma unroll
    for (int i = 0; i < 16; ++i) {
      f4v xv4 = *(const f4v*)(xr + i * 4);
      sacc += xv4[0] * cgp[i * 4] + xv4[1] * cgp[i * 4 + 1]
            + xv4[2] * cgp[i * 4 + 2] + xv4[3] * cgp[i * 4 + 3];
    }
    wp[row * 4 + sg] = sacc;
  }
  __syncthreads();
  float* wcS = (float*)sC;
  if (tid < 64) {
    const float v = wp[tid * 4] + wp[tid * 4 + 1] + wp[tid * 4 + 2] + wp[tid * 4 + 3] + cbL[0];
    wcS[tid] = v;
  }
  __syncthreads();

  // ---- h = H_hist + mlp_b + wc*x ; LN ----
  float s1l[2][4], s2l[2][4];
  #pragma unroll
  for (int a = 0; a < 2; ++a)
    #pragma unroll
    for (int r = 0; r < 4; ++r) { s1l[a][r] = 0.f; s2l[a][r] = 0.f; }
  #pragma unroll
  for (int a = 0; a < 2; ++a)
    #pragma unroll
    for (int i = 0; i < 8; ++i) {
      const int n = (i >> 1) * 64 + wc * 32 + (i & 1) * 16 + col16;
      const float mb = mlp_b[n];
      #pragma unroll
      for (int r = 0; r < 4; ++r) {
        const int row = rw + a * 16 + quad * 4 + r;
        const float xv = xb[(size_t)(p0 + row) * DIM + n];
        const float v = accH[a][i][r] + mb + wcS[row] * xv;
        accH[a][i][r] = v;
        s1l[a][r] += v;
        s2l[a][r] += v * v;
      }
    }
  #pragma unroll
  for (int a = 0; a < 2; ++a)
    #pragma unroll
    for (int r = 0; r < 4; ++r) {
      float v1 = s1l[a][r], v2 = s2l[a][r];
      v1 += __shfl_xor(v1, 1, 64); v2 += __shfl_xor(v2, 1, 64);
      v1 += __shfl_xor(v1, 2, 64); v2 += __shfl_xor(v2, 2, 64);
      v1 += __shfl_xor(v1, 4, 64); v2 += __shfl_xor(v2, 4, 64);
      v1 += __shfl_xor(v1, 8, 64); v2 += __shfl_xor(v2, 8, 64);
      s1l[a][r] = v1; s2l[a][r] = v2;
    }
  float* Ls = (float*)(sC + 256);
  float* Lq = (float*)(sC + 768);
  if (col16 == 0) {
    #pragma unroll
    for (int a = 0; a < 2; ++a)
      #pragma unroll
      for (int r = 0; r < 4; ++r) {
        const int row = rw + a * 16 + quad * 4 + r;
        Ls[wc * 64 + row] = s1l[a][r];
        Lq[wc * 64 + row] = s2l[a][r];
      }
  }
  __syncthreads();

  #pragma unroll
  for (int a = 0; a < 2; ++a) {
    float mean_[4], rstd_[4];
    #pragma unroll
    for (int r = 0; r < 4; ++r) {
      const int row = rw + a * 16 + quad * 4 + r;
      const float S1 = Ls[row] + Ls[64 + row];
      const float S2 = Lq[row] + Lq[64 + row];
      const float mean = S1 * (1.0f / 256.0f);
      const float var = S2 * (1.0f / 256.0f) - mean * mean;
      mean_[r] = mean;
      rstd_[r] = rsqrtf(fmaxf(var, 0.f) + 1e-5f);
    }
    #pragma unroll
    for (int i = 0; i < 8; ++i) {
      const int n = (i >> 1) * 64 + wc * 32 + (i & 1) * 16 + col16;
      const float g = ln_g[n];
      const float be = ln_b[n];
      #pragma unroll
      for (int r = 0; r < 4; ++r) {
        const int row = rw + a * 16 + quad * 4 + r;
        const float y = (accH[a][i][r] - mean_[r]) * rstd_[r] * g + be;
        out[((size_t)b * SEQ + p0 + row) * DIM + n] = y;
      }
    }
  }

  // ---- origin passthrough ----
  {
    const int row = tid >> 2, cs = (tid & 3) * 64;
    const float* src = xb + (size_t)(p0 + row) * DIM + cs;
    float* dst = out + ORIGIN_OFF + ((size_t)b * SEQ + p0 + row) * DIM + cs;
    #pragma unroll
    for (int j = 0; j < 16; ++j)
      *(f4v*)(dst + j * 4) = *(const f4v*)(src + j * 4);
  }
}

extern "C" void kernel_launch(void* const* d_in, const int* in_sizes, int n_in,
                              void* d_out, int out_size, void* d_ws, size_t ws_size,
                              hipStream_t stream) {
  const float* x      = (const float*)d_in[0];
  const float* mlp_w  = (const float*)d_in[1];
  const float* mlp_b  = (const float*)d_in[2];
  const float* his_w  = (const float*)d_in[3];
  const float* his_b  = (const float*)d_in[4];
  const float* cur_w  = (const float*)d_in[5];
  const float* cur_b  = (const float*)d_in[6];
  const float* wl_w   = (const float*)d_in[7];
  const float* wl_b   = (const float*)d_in[8];
  const float* gate_w = (const float*)d_in[9];
  const float* gate_b = (const float*)d_in[10];
  const float* ln_g   = (const float*)d_in[11];
  const float* ln_b   = (const float*)d_in[12];

  unsigned short* ws = (unsigned short*)d_ws;

  prep_w<<<dim3(320), 256, 0, stream>>>(wl_w, his_w, mlp_w, ws);
  prep_xt<<<dim3(32, 4, 32), 256, 0, stream>>>(x, ws + XT_OFF);
  tfs_kernel<<<dim3(32, 32), 256, 0, stream>>>(
      x, mlp_b, his_b, cur_w, cur_b, wl_b, gate_w, gate_b,
      ln_g, ln_b, ws, (float*)d_out);
}